// Round 7
// baseline (230.587 us; speedup 1.0000x reference)
//
#include <hip/hip_runtime.h>
#include <math.h>

#define BB 512
#define SS 128
#define KK 4
#define HH 128
#define DD 512   // K*H

typedef __attribute__((ext_vector_type(8))) short bf16x8;
typedef __attribute__((ext_vector_type(4))) float f32x4;

__device__ __forceinline__ unsigned short f2bf(float f) {
  unsigned u = __float_as_uint(f);
  unsigned r = u + 0x7fffu + ((u >> 16) & 1u);   // RNE (no NaNs in this data)
  return (unsigned short)(r >> 16);
}
__device__ __forceinline__ float bfhi(unsigned u) { return __uint_as_float(u & 0xffff0000u); }
__device__ __forceinline__ float bflo(unsigned u) { return __uint_as_float(u << 16); }

// ---------------------------------------------------------------------------
// prep: item[b][s][h] fp32 -> item_t[s][b][h] bf16 (rows intact, both sides
// coalesced), and w fp32 -> bf16 flat.  (R5-proven)
// ---------------------------------------------------------------------------
__global__ __launch_bounds__(256) void prep_k(
    const float* __restrict__ item, const float* __restrict__ w,
    unsigned short* __restrict__ item_t, unsigned short* __restrict__ w_bf)
{
  const int blk = blockIdx.x, t = threadIdx.x;
  if (blk < 8192) {
    const int rid = blk * 8 + (t >> 5);       // rid = b*SS + s
    const int b = rid >> 7, s = rid & 127;
    const int c = t & 31;
    float4 v = ((const float4*)(item + (size_t)rid * HH))[c];
    ushort4 o;
    o.x = f2bf(v.x); o.y = f2bf(v.y); o.z = f2bf(v.z); o.w = f2bf(v.w);
    ((ushort4*)(item_t + ((size_t)s * BB + b) * HH))[c] = o;
  } else {
    size_t base = (size_t)(blk - 8192) * 2048 + t;
    const float4* src = (const float4*)w;
    ushort4* dst = (ushort4*)w_bf;
    #pragma unroll
    for (int j = 0; j < 8; j++) {
      float4 v = src[base + 256 * j];
      ushort4 o;
      o.x = f2bf(v.x); o.y = f2bf(v.y); o.z = f2bf(v.z); o.w = f2bf(v.w);
      dst[base + 256 * j] = o;
    }
  }
}

// ---------------------------------------------------------------------------
// hat[b][k][s][h'] = sum_h item[b][s][h] * w[s][k*HH+h'][h]   (bf16 in/out)
// R5-proven: transposed bf16 inputs -> 8KB-contiguous wave staging reads;
// s-major grid keeps one s's 16 tiles on one XCD; XOR-swizzled LDS.
// ---------------------------------------------------------------------------
__global__ __launch_bounds__(256) void einsum_mfma(
    const unsigned short* __restrict__ At,  // bf16 [S][B][H]
    const unsigned short* __restrict__ W,   // bf16 [S][D][H]
    unsigned short* __restrict__ hat)       // bf16 [B][K][S][H]
{
  __shared__ unsigned short Al[128 * 64];
  __shared__ unsigned short Wl[128 * 64];
  const int s  = blockIdx.x;
  const int b0 = (blockIdx.y & 3) * 128;
  const int dt = blockIdx.y >> 2;
  const int d0 = dt * 128;
  const int t  = threadIdx.x;
  const int lane = t & 63, wv = t >> 6;
  const int qm = wv & 1, qn = wv >> 1;
  const int n16 = lane & 15, kq = lane >> 4;
  const int sr = t >> 3, sc = t & 7;        // staging row-base / 16B col

  const unsigned short* Abase = At + ((size_t)s * BB + b0) * HH;
  const unsigned short* Wbase = W + ((size_t)s * DD + d0) * HH;

  f32x4 acc[4][4] = {};
  for (int ks = 0; ks < 128; ks += 64) {
    #pragma unroll
    for (int j = 0; j < 4; j++) {
      const int r = sr + 32 * j;
      uint4 va = *(const uint4*)(Abase + (size_t)r * HH + ks + sc * 8);
      uint4 vw = *(const uint4*)(Wbase + (size_t)r * HH + ks + sc * 8);
      const int goff = ((sc + r) & 7) * 8;
      *(uint4*)&Al[r * 64 + goff] = va;
      *(uint4*)&Wl[r * 64 + goff] = vw;
    }
    __syncthreads();
    #pragma unroll
    for (int kk = 0; kk < 2; kk++) {
      bf16x8 af[4], bfr[4];
      #pragma unroll
      for (int i = 0; i < 4; i++) {
        const int ra = qm * 64 + i * 16 + n16;   // w rows (h')
        const int rb = qn * 64 + i * 16 + n16;   // item rows (b)
        af[i]  = *(const bf16x8*)&Wl[ra * 64 + ((kk * 4 + kq + ra) & 7) * 8];
        bfr[i] = *(const bf16x8*)&Al[rb * 64 + ((kk * 4 + kq + rb) & 7) * 8];
      }
      #pragma unroll
      for (int i = 0; i < 4; i++)
        #pragma unroll
        for (int j = 0; j < 4; j++)
          acc[i][j] = __builtin_amdgcn_mfma_f32_16x16x32_bf16(af[i], bfr[j], acc[i][j], 0, 0, 0);
    }
    __syncthreads();
  }

  #pragma unroll
  for (int j = 0; j < 4; j++) {
    const int b = b0 + qn * 64 + j * 16 + n16;
    unsigned short* orow = hat + (((size_t)b * KK + dt) * SS + s) * HH;
    #pragma unroll
    for (int i = 0; i < 4; i++) {
      const int h = qm * 64 + i * 16 + kq * 4;
      ushort4 o;
      o.x = f2bf(acc[i][j][0]); o.y = f2bf(acc[i][j][1]);
      o.z = f2bf(acc[i][j][2]); o.w = f2bf(acc[i][j][3]);
      *(ushort4*)(orow + h) = o;
    }
  }
}

// ---------------------------------------------------------------------------
// Batch-axis softmax (legacy torch dim=0) on [B][K][S]-layout cw -> sw.
// LDS transpose tile, fully coalesced both directions. (R6-verified)
// Mask-zeroing applied downstream in routing_k.
// ---------------------------------------------------------------------------
__global__ __launch_bounds__(256) void softmax_k(
    const float* __restrict__ cw, float* __restrict__ sw)
{
  __shared__ float T[512 * 33];
  __shared__ float red[2][8][32];
  const int s0 = blockIdx.x * 32, k = blockIdx.y, t = threadIdx.x;
  const int bg = t >> 3, c = t & 7;

  #pragma unroll
  for (int i = 0; i < 16; i++) {
    const int b = i * 32 + bg;
    float4 v = *(const float4*)(cw + ((size_t)b * KK + k) * SS + s0 + c * 4);
    float* Tr = &T[b * 33 + c * 4];
    Tr[0] = v.x; Tr[1] = v.y; Tr[2] = v.z; Tr[3] = v.w;
  }
  __syncthreads();

  const int sc = t & 31, grp = t >> 5;
  float mx = -3.4e38f;
  #pragma unroll 8
  for (int i = 0; i < 64; i++)
    mx = fmaxf(mx, T[(grp * 64 + i) * 33 + sc]);
  red[0][grp][sc] = mx;
  __syncthreads();
  float mall = red[0][0][sc];
  #pragma unroll
  for (int g = 1; g < 8; g++) mall = fmaxf(mall, red[0][g][sc]);
  float sm = 0.f;
  #pragma unroll 8
  for (int i = 0; i < 64; i++) {
    float* p = &T[(grp * 64 + i) * 33 + sc];
    float e = __expf(*p - mall);
    *p = e; sm += e;
  }
  red[1][grp][sc] = sm;
  __syncthreads();
  float tot = 0.f;
  #pragma unroll
  for (int g = 0; g < 8; g++) tot += red[1][g][sc];
  const float inv = 1.f / tot;
  #pragma unroll 8
  for (int i = 0; i < 64; i++)
    T[(grp * 64 + i) * 33 + sc] *= inv;
  __syncthreads();

  #pragma unroll
  for (int i = 0; i < 16; i++) {
    const int b = i * 32 + bg;
    const float* Tr = &T[b * 33 + c * 4];
    *(float4*)(sw + ((size_t)b * KK + k) * SS + s0 + c * 4) =
        make_float4(Tr[0], Tr[1], Tr[2], Tr[3]);
  }
}

// ---------------------------------------------------------------------------
// One routing iteration for ALL 4 k of one b per block (grid 512).
// Double-buffered LDS slabs: slab k+1's global loads are issued into
// registers BEFORE slab k's compute and ds-written after -> load latency
// hidden behind ph1/ph2. cw/sw in [B][K][S] (contiguous per block).
//   mode 0: uniform sw from mask, cw  = delta
//   mode 1: sw from sw_in (masked), cw += delta
//   mode 2: sw from sw_in (masked), out = squash(cap)  (no ph2)
// ---------------------------------------------------------------------------
__global__ __launch_bounds__(256) void routing_k(
    const unsigned short* __restrict__ hat, const float* __restrict__ mask,
    const float* __restrict__ sw_in, float* __restrict__ cw,
    float* __restrict__ out, int mode)
{
  __shared__ unsigned short hat_l[2][128 * 136];
  __shared__ float sw_l[4][128];
  __shared__ float4 red4[8][32];
  __shared__ float4 cq4[32];
  const int b = blockIdx.x, t = threadIdx.x;

  // sw for all 4 k (contiguous 512 floats in [B][K][S])
  {
    const float mk = mask[(size_t)b * SS + (t & 127)];
    if (mode == 0) {
      if (t < 128) {
        const float v = (mk == 0.f) ? 0.f : (1.f / 512.f);
        #pragma unroll
        for (int k = 0; k < 4; k++) sw_l[k][t] = v;
      }
    } else {
      const float* sp = sw_in + (size_t)b * 512;
      float v0 = sp[t], v1 = sp[t + 256];
      sw_l[t >> 7][t & 127]       = (mk == 0.f) ? 0.f : v0;
      sw_l[2 + (t >> 7)][t & 127] = (mk == 0.f) ? 0.f : v1;
    }
  }

  const uint4* hbase = (const uint4*)(hat + (size_t)b * KK * SS * HH);
  const int src = t >> 4, scc = t & 15;      // stage row / 16B col (8/thread)

  // pre-stage slab k=0 into buf 0
  {
    const uint4* hp = hbase;
    #pragma unroll
    for (int j = 0; j < 8; j++) {
      const int f = t + 256 * j;
      *(uint4*)&hat_l[0][(f >> 4) * 136 + (f & 15) * 8] = hp[f];
    }
  }
  __syncthreads();

  for (int k = 0; k < 4; k++) {
    const int cur = k & 1;
    // issue next slab's global loads now (held in regs through compute)
    uint4 stg[8];
    if (k < 3) {
      const uint4* hp = hbase + (size_t)(k + 1) * 2048;
      #pragma unroll
      for (int j = 0; j < 8; j++) stg[j] = hp[t + 256 * j];
    }

    // phase 1: cap[h] = sum_s sw[k][s]*hat[s][h]
    {
      const int h4 = t & 31, sg = t >> 5;
      float4 a = make_float4(0.f, 0.f, 0.f, 0.f);
      #pragma unroll 4
      for (int i = 0; i < 16; i++) {
        const int s = sg * 16 + i;
        uint2 v = *(const uint2*)&hat_l[cur][s * 136 + h4 * 4];
        float wv = sw_l[k][s];
        a.x = fmaf(wv, bflo(v.x), a.x);
        a.y = fmaf(wv, bfhi(v.x), a.y);
        a.z = fmaf(wv, bflo(v.y), a.z);
        a.w = fmaf(wv, bfhi(v.y), a.w);
      }
      red4[sg][h4] = a;
    }
    __syncthreads();

    if (t < 32) {
      float4 cap = red4[0][t];
      #pragma unroll
      for (int sg = 1; sg < 8; sg++) {
        float4 r = red4[sg][t];
        cap.x += r.x; cap.y += r.y; cap.z += r.z; cap.w += r.w;
      }
      float sq = cap.x * cap.x + cap.y * cap.y + cap.z * cap.z + cap.w * cap.w;
      #pragma unroll
      for (int o = 16; o; o >>= 1) sq += __shfl_xor(sq, o);
      const float n = sq;
      const float fac = n / (1.f + n) / sqrtf(n + 1e-9f);
      cap.x *= fac; cap.y *= fac; cap.z *= fac; cap.w *= fac;
      cq4[t] = cap;
      if (mode == 2)
        ((float4*)(out + ((size_t)b * KK + k) * HH))[t] = cap;
    }
    __syncthreads();

    if (mode < 2) {
      // phase 2: delta[s] = dot(hat[s][:], cq) — lane pair per s
      const int s = t >> 1, hh = t & 1;
      const uint4* row = (const uint4*)&hat_l[cur][s * 136 + hh * 64];
      float d = 0.f;
      #pragma unroll
      for (int j = 0; j < 8; j++) {
        uint4 v = row[j];
        float4 qa = cq4[hh * 16 + 2 * j];
        float4 qb = cq4[hh * 16 + 2 * j + 1];
        d += bflo(v.x) * qa.x + bfhi(v.x) * qa.y
           + bflo(v.y) * qa.z + bfhi(v.y) * qa.w
           + bflo(v.z) * qb.x + bfhi(v.z) * qb.y
           + bflo(v.w) * qb.z + bfhi(v.w) * qb.w;
      }
      d += __shfl_xor(d, 1);
      if (hh == 0) {
        float* p = cw + ((size_t)b * KK + k) * SS + s;   // contiguous in s
        if (mode == 0) *p = d; else *p += d;
      }
    }

    // write next slab to the other buffer; barrier covers visibility AND
    // protects hat_l[cur] (fully consumed above) for the k+2 restage.
    if (k < 3) {
      const int nxt = cur ^ 1;
      #pragma unroll
      for (int j = 0; j < 8; j++) {
        const int f = t + 256 * j;
        *(uint4*)&hat_l[nxt][(f >> 4) * 136 + (f & 15) * 8] = stg[j];
      }
    }
    __syncthreads();
  }
}

extern "C" void kernel_launch(void* const* d_in, const int* in_sizes, int n_in,
                              void* d_out, int out_size, void* d_ws, size_t ws_size,
                              hipStream_t stream) {
  const float* item_eb = (const float*)d_in[0];   // [B,S,H]
  const float* mask    = (const float*)d_in[1];   // [B,S]
  const float* w       = (const float*)d_in[2];   // [1,S,K*H,H]
  float* out = (float*)d_out;                     // [B,K,H]

  char* ws = (char*)d_ws;
  unsigned short* hat_bf  = (unsigned short*)ws;               // 67.1 MB [B][K][S][H]
  unsigned short* item_t  = (unsigned short*)(ws + 67108864);  // 16.8 MB [S][B][H]
  unsigned short* w_bf    = (unsigned short*)(ws + 83886080);  // 16.8 MB [S][D][H]
  float* cw  = (float*)(ws + 100663296);                       // [B][K][S]
  float* swb = (float*)(ws + 101711872);                       // [B][K][S]

  prep_k<<<dim3(9216), 256, 0, stream>>>(item_eb, w, item_t, w_bf);
  einsum_mfma<<<dim3(128, 16), 256, 0, stream>>>(item_t, w_bf, hat_bf);

  routing_k<<<dim3(BB), 256, 0, stream>>>(hat_bf, mask, nullptr, cw, out, 0);
  softmax_k<<<dim3(4, KK), 256, 0, stream>>>(cw, swb);
  routing_k<<<dim3(BB), 256, 0, stream>>>(hat_bf, mask, swb, cw, out, 1);
  softmax_k<<<dim3(4, KK), 256, 0, stream>>>(cw, swb);
  routing_k<<<dim3(BB), 256, 0, stream>>>(hat_bf, mask, swb, cw, out, 2);
}

// Round 8
// 204.985 us; speedup vs baseline: 1.1249x; 1.1249x over previous
//
#include <hip/hip_runtime.h>
#include <math.h>

#define BB 512
#define SS 128
#define KK 4
#define HH 128
#define DD 512   // K*H

typedef __attribute__((ext_vector_type(8))) short bf16x8;
typedef __attribute__((ext_vector_type(4))) float f32x4;

__device__ __forceinline__ unsigned short f2bf(float f) {
  unsigned u = __float_as_uint(f);
  unsigned r = u + 0x7fffu + ((u >> 16) & 1u);   // RNE (no NaNs in this data)
  return (unsigned short)(r >> 16);
}
__device__ __forceinline__ float bfhi(unsigned u) { return __uint_as_float(u & 0xffff0000u); }
__device__ __forceinline__ float bflo(unsigned u) { return __uint_as_float(u << 16); }
__device__ __forceinline__ unsigned pk2(float a, float b) {
  return (unsigned)f2bf(a) | ((unsigned)f2bf(b) << 16);
}
__device__ __forceinline__ bf16x8 cvt8(float4 a, float4 b) {
  union { unsigned u[4]; bf16x8 v; } r;
  r.u[0] = pk2(a.x, a.y); r.u[1] = pk2(a.z, a.w);
  r.u[2] = pk2(b.x, b.y); r.u[3] = pk2(b.z, b.w);
  return r.v;
}

// ---------------------------------------------------------------------------
// hat[b][k][s][h'] = sum_h item[b][s][h] * w[s][k*HH+h'][h]
// Direct-fragment MFMA GEMM: NO LDS, NO barriers, no prep kernel. Each lane
// loads its A/B fragments straight from global fp32 (one 128-B line per row
// per K-step; every line read once per block, shared x4 via XCD-local L2 —
// s-major grid keeps one s's 16 tiles on one XCD), converts to bf16 in VALU
// (hidden under MFMA/load latency), accumulates 4 K-steps of 16x16x32.
// A=w rows (h'), B=item rows (b) => 4 acc regs = 4 consecutive h' -> ushort4.
// ---------------------------------------------------------------------------
__global__ __launch_bounds__(256) void einsum_mfma(
    const float* __restrict__ item,   // fp32 [B][S][H]
    const float* __restrict__ w,      // fp32 [S][D][H]
    unsigned short* __restrict__ hat) // bf16 [B][K][S][H]
{
  const int s  = blockIdx.x;
  const int b0 = (blockIdx.y & 3) * 128;
  const int dt = blockIdx.y >> 2;
  const int d0 = dt * 128;
  const int t  = threadIdx.x;
  const int lane = t & 63, wv = t >> 6;
  const int qm = wv & 1, qn = wv >> 1;        // wave quadrant (64x64)
  const int n16 = lane & 15, kq = lane >> 4;

  // per-lane row pointers (invariant over K-steps)
  const float* pw[4];
  const float* pi[4];
  #pragma unroll
  for (int i = 0; i < 4; i++) {
    pw[i] = w    + ((size_t)s * DD + d0 + qm * 64 + i * 16 + n16) * HH;
    pi[i] = item + ((size_t)(b0 + qn * 64 + i * 16 + n16) * SS + s) * HH;
  }

  f32x4 acc[4][4] = {};
  #pragma unroll
  for (int ks = 0; ks < 4; ks++) {
    const int kb = ks * 32 + kq * 8;
    bf16x8 af[4], bfr[4];
    #pragma unroll
    for (int i = 0; i < 4; i++) {
      float4 w0 = *(const float4*)(pw[i] + kb);
      float4 w1 = *(const float4*)(pw[i] + kb + 4);
      float4 a0 = *(const float4*)(pi[i] + kb);
      float4 a1 = *(const float4*)(pi[i] + kb + 4);
      af[i]  = cvt8(w0, w1);
      bfr[i] = cvt8(a0, a1);
    }
    #pragma unroll
    for (int i = 0; i < 4; i++)
      #pragma unroll
      for (int j = 0; j < 4; j++)
        acc[i][j] = __builtin_amdgcn_mfma_f32_16x16x32_bf16(af[i], bfr[j], acc[i][j], 0, 0, 0);
  }

  // D row = qm*64+i*16+kq*4+reg = h'; col = qn*64+j*16+n16 = local b
  #pragma unroll
  for (int j = 0; j < 4; j++) {
    const int b = b0 + qn * 64 + j * 16 + n16;
    unsigned short* orow = hat + (((size_t)b * KK + dt) * SS + s) * HH;
    #pragma unroll
    for (int i = 0; i < 4; i++) {
      const int h = qm * 64 + i * 16 + kq * 4;
      ushort4 o;
      o.x = f2bf(acc[i][j][0]); o.y = f2bf(acc[i][j][1]);
      o.z = f2bf(acc[i][j][2]); o.w = f2bf(acc[i][j][3]);
      *(ushort4*)(orow + h) = o;
    }
  }
}

// ---------------------------------------------------------------------------
// Batch-axis softmax (legacy torch dim=0) + mask zeroing. Grid (S,K).
// (R5-verified)
// ---------------------------------------------------------------------------
__global__ __launch_bounds__(256) void softmax_k(
    const float* __restrict__ cw, const float* __restrict__ mask,
    float* __restrict__ sw)
{
  __shared__ float rbuf[4];
  const int s = blockIdx.x, k = blockIdx.y, t = threadIdx.x;
  const size_t base = ((size_t)k * SS + s) * BB;
  float v0 = cw[base + t], v1 = cw[base + 256 + t];
  float m = fmaxf(v0, v1);
  #pragma unroll
  for (int o = 32; o; o >>= 1) m = fmaxf(m, __shfl_xor(m, o));
  if ((t & 63) == 0) rbuf[t >> 6] = m;
  __syncthreads();
  m = fmaxf(fmaxf(rbuf[0], rbuf[1]), fmaxf(rbuf[2], rbuf[3]));
  float e0 = expf(v0 - m), e1 = expf(v1 - m);
  float ssum = e0 + e1;
  #pragma unroll
  for (int o = 32; o; o >>= 1) ssum += __shfl_xor(ssum, o);
  __syncthreads();
  if ((t & 63) == 0) rbuf[t >> 6] = ssum;
  __syncthreads();
  float inv = 1.f / (rbuf[0] + rbuf[1] + rbuf[2] + rbuf[3]);
  float m0 = mask[(size_t)t * SS + s];
  float m1 = mask[(size_t)(t + 256) * SS + s];
  sw[base + t]       = (m0 == 0.f) ? 0.f : e0 * inv;
  sw[base + 256 + t] = (m1 == 0.f) ? 0.f : e1 * inv;
}

// ---------------------------------------------------------------------------
// One routing iteration per (b,k). Stage the 32 KB bf16 hat slab in LDS once
// (2048 uint4 = 8 per thread); both phases read from LDS.  (R5-verified)
//   mode 0: uniform sw from mask, cw  = delta
//   mode 1: sw from sw_in,        cw += delta
//   mode 2: sw from sw_in,        out = squash(cap)
// ---------------------------------------------------------------------------
__global__ __launch_bounds__(256) void routing_k(
    const unsigned short* __restrict__ hat, const float* __restrict__ mask,
    const float* __restrict__ sw_in, float* __restrict__ cw,
    float* __restrict__ out, int mode)
{
  __shared__ unsigned short hat_l[128 * 136];
  __shared__ float sw_l[128];
  __shared__ float4 red4[8][32];
  __shared__ float4 cq4[32];
  const int b = blockIdx.x, k = blockIdx.y, t = threadIdx.x;

  if (t < 128) {
    sw_l[t] = (mode == 0)
      ? ((mask[(size_t)b * SS + t] == 0.f) ? 0.f : (1.f / 512.f))
      : ((mask[(size_t)b * SS + t] == 0.f) ? 0.f
         : sw_in[((size_t)k * SS + t) * BB + b]);
  }
  const uint4* hp = (const uint4*)(hat + ((size_t)b * KK + k) * SS * HH);
  #pragma unroll
  for (int j = 0; j < 8; j++) {            // 2048 uint4 total
    const int f = t + 256 * j;
    const int s = f >> 4, c = f & 15;
    *(uint4*)&hat_l[s * 136 + c * 8] = hp[f];
  }
  __syncthreads();

  // phase 1: cap[h] = sum_s sw[s]*hat[s][h]; 8 s-groups x 32 uint2 cols
  {
    const int h4 = t & 31, sg = t >> 5;
    float4 a = make_float4(0.f, 0.f, 0.f, 0.f);
    #pragma unroll 4
    for (int i = 0; i < 16; i++) {
      const int s = sg * 16 + i;
      uint2 v = *(const uint2*)&hat_l[s * 136 + h4 * 4];
      float wv = sw_l[s];
      a.x = fmaf(wv, bflo(v.x), a.x);
      a.y = fmaf(wv, bfhi(v.x), a.y);
      a.z = fmaf(wv, bflo(v.y), a.z);
      a.w = fmaf(wv, bfhi(v.y), a.w);
    }
    red4[sg][h4] = a;
  }
  __syncthreads();

  if (t < 32) {
    float4 cap = red4[0][t];
    #pragma unroll
    for (int sg = 1; sg < 8; sg++) {
      float4 r = red4[sg][t];
      cap.x += r.x; cap.y += r.y; cap.z += r.z; cap.w += r.w;
    }
    float sq = cap.x * cap.x + cap.y * cap.y + cap.z * cap.z + cap.w * cap.w;
    #pragma unroll
    for (int o = 16; o; o >>= 1) sq += __shfl_xor(sq, o);
    const float n = sq;
    const float fac = n / (1.f + n) / sqrtf(n + 1e-9f);
    cap.x *= fac; cap.y *= fac; cap.z *= fac; cap.w *= fac;
    cq4[t] = cap;
    if (mode == 2)
      ((float4*)(out + ((size_t)b * KK + k) * HH))[t] = cap;
  }
  __syncthreads();

  if (mode < 2) {
    // phase 2: delta[s] = dot(hat[s][:], cq) — lane pair per s, from LDS
    const int s = t >> 1, hh = t & 1;
    const uint4* row = (const uint4*)&hat_l[s * 136 + hh * 64];
    float d = 0.f;
    #pragma unroll
    for (int j = 0; j < 8; j++) {
      uint4 v = row[j];
      float4 qa = cq4[hh * 16 + 2 * j];
      float4 qb = cq4[hh * 16 + 2 * j + 1];
      d += bflo(v.x) * qa.x + bfhi(v.x) * qa.y
         + bflo(v.y) * qa.z + bfhi(v.y) * qa.w
         + bflo(v.z) * qb.x + bfhi(v.z) * qb.y
         + bflo(v.w) * qb.z + bfhi(v.w) * qb.w;
    }
    d += __shfl_xor(d, 1);
    if (hh == 0) {
      float* p = cw + ((size_t)k * SS + s) * BB + b;
      if (mode == 0) *p = d; else *p += d;
    }
  }
}

extern "C" void kernel_launch(void* const* d_in, const int* in_sizes, int n_in,
                              void* d_out, int out_size, void* d_ws, size_t ws_size,
                              hipStream_t stream) {
  const float* item_eb = (const float*)d_in[0];   // [B,S,H]
  const float* mask    = (const float*)d_in[1];   // [B,S]
  const float* w       = (const float*)d_in[2];   // [1,S,K*H,H]
  float* out = (float*)d_out;                     // [B,K,H]

  char* ws = (char*)d_ws;
  unsigned short* hat_bf = (unsigned short*)ws;        // 67.1 MB bf16 [B][K][S][H]
  float* cw  = (float*)(ws + 67108864);                // 1 MB [K][S][B]
  float* swb = (float*)(ws + 68157440);                // 1 MB [K][S][B]

  einsum_mfma<<<dim3(128, 16), 256, 0, stream>>>(item_eb, w, hat_bf);

  routing_k<<<dim3(BB, KK), 256, 0, stream>>>(hat_bf, mask, nullptr, cw, out, 0);
  softmax_k<<<dim3(SS, KK), 256, 0, stream>>>(cw, mask, swb);
  routing_k<<<dim3(BB, KK), 256, 0, stream>>>(hat_bf, mask, swb, cw, out, 1);
  softmax_k<<<dim3(SS, KK), 256, 0, stream>>>(cw, mask, swb);
  routing_k<<<dim3(BB, KK), 256, 0, stream>>>(hat_bf, mask, swb, cw, out, 2);
}

// Round 9
// 189.737 us; speedup vs baseline: 1.2153x; 1.0804x over previous
//
#include <hip/hip_runtime.h>
#include <math.h>

#define BB 512
#define SS 128
#define KK 4
#define HH 128
#define DD 512   // K*H

typedef __attribute__((ext_vector_type(8))) short bf16x8;
typedef __attribute__((ext_vector_type(4))) float f32x4;

__device__ __forceinline__ unsigned short f2bf(float f) {
  unsigned u = __float_as_uint(f);
  unsigned r = u + 0x7fffu + ((u >> 16) & 1u);   // RNE (no NaNs in this data)
  return (unsigned short)(r >> 16);
}
__device__ __forceinline__ float bfhi(unsigned u) { return __uint_as_float(u & 0xffff0000u); }
__device__ __forceinline__ float bflo(unsigned u) { return __uint_as_float(u << 16); }

// async global->LDS, 16B per lane. LDS dest = wave-uniform base + lane*16.
__device__ __forceinline__ void async_cp16(const unsigned short* g, unsigned short* l) {
  __builtin_amdgcn_global_load_lds(
      (const __attribute__((address_space(1))) unsigned int*)g,
      (__attribute__((address_space(3))) unsigned int*)l, 16, 0, 0);
}

// ---------------------------------------------------------------------------
// prep: item[b][s][h] fp32 -> item_t[s][b][h] bf16 (rows intact, both sides
// coalesced), and w fp32 -> bf16 flat.  (R5-proven)
// ---------------------------------------------------------------------------
__global__ __launch_bounds__(256) void prep_k(
    const float* __restrict__ item, const float* __restrict__ w,
    unsigned short* __restrict__ item_t, unsigned short* __restrict__ w_bf)
{
  const int blk = blockIdx.x, t = threadIdx.x;
  if (blk < 8192) {
    const int rid = blk * 8 + (t >> 5);       // rid = b*SS + s
    const int b = rid >> 7, s = rid & 127;
    const int c = t & 31;
    float4 v = ((const float4*)(item + (size_t)rid * HH))[c];
    ushort4 o;
    o.x = f2bf(v.x); o.y = f2bf(v.y); o.z = f2bf(v.z); o.w = f2bf(v.w);
    ((ushort4*)(item_t + ((size_t)s * BB + b) * HH))[c] = o;
  } else {
    size_t base = (size_t)(blk - 8192) * 2048 + t;
    const float4* src = (const float4*)w;
    ushort4* dst = (ushort4*)w_bf;
    #pragma unroll
    for (int j = 0; j < 8; j++) {
      float4 v = src[base + 256 * j];
      ushort4 o;
      o.x = f2bf(v.x); o.y = f2bf(v.y); o.z = f2bf(v.z); o.w = f2bf(v.w);
      dst[base + 256 * j] = o;
    }
  }
}

// ---------------------------------------------------------------------------
// hat[b][k][s][h'] = sum_h item[b][s][h] * w[s][k*HH+h'][h]   (bf16 in/out)
// R5 structure + global_load_lds staging. Source-permuted swizzle: LDS
// slot (row r, chunk g) holds global chunk (g-r)&7, so the R5 XOR-swizzled
// frag reads are unchanged and bank-conflict-free. No VGPR round-trip.
// ---------------------------------------------------------------------------
__global__ __launch_bounds__(256) void einsum_mfma(
    const unsigned short* __restrict__ At,  // bf16 [S][B][H]
    const unsigned short* __restrict__ W,   // bf16 [S][D][H]
    unsigned short* __restrict__ hat)       // bf16 [B][K][S][H]
{
  __shared__ unsigned short Al[128 * 64];
  __shared__ unsigned short Wl[128 * 64];
  const int s  = blockIdx.x;
  const int b0 = (blockIdx.y & 3) * 128;
  const int dt = blockIdx.y >> 2;
  const int d0 = dt * 128;
  const int t  = threadIdx.x;
  const int lane = t & 63, wv = t >> 6;
  const int qm = wv & 1, qn = wv >> 1;
  const int n16 = lane & 15, kq = lane >> 4;

  const unsigned short* Abase = At + ((size_t)s * BB + b0) * HH;
  const unsigned short* Wbase = W + ((size_t)s * DD + d0) * HH;

  f32x4 acc[4][4] = {};
  for (int ks = 0; ks < 128; ks += 64) {
    // stage 16KB per array: 4 calls/wave; slot m = wv*256 + c*64 + lane
    // (uint4 units); r = m>>3, g = m&7; source chunk = (g-r)&7 (swizzle).
    #pragma unroll
    for (int c = 0; c < 4; c++) {
      const int m = wv * 256 + c * 64 + lane;
      const int r = m >> 3, g = m & 7;
      const int cc = (g - r) & 7;
      const int ldsoff = wv * 2048 + c * 512;   // shorts, wave-uniform
      async_cp16(Abase + (size_t)r * HH + ks + cc * 8, &Al[ldsoff]);
      async_cp16(Wbase + (size_t)r * HH + ks + cc * 8, &Wl[ldsoff]);
    }
    __syncthreads();
    #pragma unroll
    for (int kk = 0; kk < 2; kk++) {
      bf16x8 af[4], bfr[4];
      #pragma unroll
      for (int i = 0; i < 4; i++) {
        const int ra = qm * 64 + i * 16 + n16;   // w rows (h')
        const int rb = qn * 64 + i * 16 + n16;   // item rows (b)
        af[i]  = *(const bf16x8*)&Wl[ra * 64 + ((kk * 4 + kq + ra) & 7) * 8];
        bfr[i] = *(const bf16x8*)&Al[rb * 64 + ((kk * 4 + kq + rb) & 7) * 8];
      }
      #pragma unroll
      for (int i = 0; i < 4; i++)
        #pragma unroll
        for (int j = 0; j < 4; j++)
          acc[i][j] = __builtin_amdgcn_mfma_f32_16x16x32_bf16(af[i], bfr[j], acc[i][j], 0, 0, 0);
    }
    __syncthreads();
  }

  // D row = qm*64+i*16+kq*4+reg = h'; col = qn*64+j*16+n16 = local b
  #pragma unroll
  for (int j = 0; j < 4; j++) {
    const int b = b0 + qn * 64 + j * 16 + n16;
    unsigned short* orow = hat + (((size_t)b * KK + dt) * SS + s) * HH;
    #pragma unroll
    for (int i = 0; i < 4; i++) {
      const int h = qm * 64 + i * 16 + kq * 4;
      ushort4 o;
      o.x = f2bf(acc[i][j][0]); o.y = f2bf(acc[i][j][1]);
      o.z = f2bf(acc[i][j][2]); o.w = f2bf(acc[i][j][3]);
      *(ushort4*)(orow + h) = o;
    }
  }
}

// ---------------------------------------------------------------------------
// Batch-axis softmax (legacy torch dim=0) + mask zeroing. Grid (S,K).
// (R5-verified; cw/sw in [K][S][B])
// ---------------------------------------------------------------------------
__global__ __launch_bounds__(256) void softmax_k(
    const float* __restrict__ cw, const float* __restrict__ mask,
    float* __restrict__ sw)
{
  __shared__ float rbuf[4];
  const int s = blockIdx.x, k = blockIdx.y, t = threadIdx.x;
  const size_t base = ((size_t)k * SS + s) * BB;
  float v0 = cw[base + t], v1 = cw[base + 256 + t];
  float m = fmaxf(v0, v1);
  #pragma unroll
  for (int o = 32; o; o >>= 1) m = fmaxf(m, __shfl_xor(m, o));
  if ((t & 63) == 0) rbuf[t >> 6] = m;
  __syncthreads();
  m = fmaxf(fmaxf(rbuf[0], rbuf[1]), fmaxf(rbuf[2], rbuf[3]));
  float e0 = expf(v0 - m), e1 = expf(v1 - m);
  float ssum = e0 + e1;
  #pragma unroll
  for (int o = 32; o; o >>= 1) ssum += __shfl_xor(ssum, o);
  __syncthreads();
  if ((t & 63) == 0) rbuf[t >> 6] = ssum;
  __syncthreads();
  float inv = 1.f / (rbuf[0] + rbuf[1] + rbuf[2] + rbuf[3]);
  float m0 = mask[(size_t)t * SS + s];
  float m1 = mask[(size_t)(t + 256) * SS + s];
  sw[base + t]       = (m0 == 0.f) ? 0.f : e0 * inv;
  sw[base + 256 + t] = (m1 == 0.f) ? 0.f : e1 * inv;
}

// ---------------------------------------------------------------------------
// One routing iteration per (b,k). hat slab staged via global_load_lds into
// a FLAT 32KB LDS array with per-row source rotation: LDS (row s, chunk g)
// holds global chunk (g-s)&15. ph1/ph2 read with rotated indices (same
// bank-spread as the R5 padded layout, no padding allowed by the DMA).
//   mode 0: uniform sw from mask, cw  = delta
//   mode 1: sw from sw_in (masked), cw += delta
//   mode 2: sw from sw_in (masked), out = squash(cap)
// ---------------------------------------------------------------------------
__global__ __launch_bounds__(256) void routing_k(
    const unsigned short* __restrict__ hat, const float* __restrict__ mask,
    const float* __restrict__ sw_in, float* __restrict__ cw,
    float* __restrict__ out, int mode)
{
  __shared__ unsigned short hat_l[128 * 128];   // flat, source-rotated
  __shared__ float sw_l[128];
  __shared__ float4 red4[8][32];
  __shared__ float4 cq4[32];
  const int b = blockIdx.x, k = blockIdx.y, t = threadIdx.x;
  const int lane = t & 63, wv = t >> 6;

  if (t < 128) {
    sw_l[t] = (mask[(size_t)b * SS + t] == 0.f) ? 0.f
      : (mode == 0 ? (1.f / 512.f) : sw_in[((size_t)k * SS + t) * BB + b]);
  }
  // stage 32KB: 8 calls/wave; slot m = wv*512 + c*64 + lane (uint4 units);
  // r = m>>4, g = m&15; source chunk = (g-r)&15.
  const unsigned short* hbase = hat + ((size_t)b * KK + k) * SS * HH;
  #pragma unroll
  for (int c = 0; c < 8; c++) {
    const int m = wv * 512 + c * 64 + lane;
    const int r = m >> 4, g = m & 15;
    const int cc = (g - r) & 15;
    async_cp16(hbase + (size_t)r * HH + cc * 8, &hat_l[wv * 4096 + c * 512]);
  }
  __syncthreads();

  // phase 1: cap[h] = sum_s sw[s]*hat[s][h]; rotated chunk lookup
  {
    const int h4 = t & 31, sg = t >> 5;          // 8-B col / s-group
    const int hc = h4 >> 1, half = h4 & 1;
    float4 a = make_float4(0.f, 0.f, 0.f, 0.f);
    #pragma unroll 4
    for (int i = 0; i < 16; i++) {
      const int s = sg * 16 + i;
      uint2 v = *(const uint2*)&hat_l[s * 128 + ((hc + s) & 15) * 8 + half * 4];
      float wvv = sw_l[s];
      a.x = fmaf(wvv, bflo(v.x), a.x);
      a.y = fmaf(wvv, bfhi(v.x), a.y);
      a.z = fmaf(wvv, bflo(v.y), a.z);
      a.w = fmaf(wvv, bfhi(v.y), a.w);
    }
    red4[sg][h4] = a;
  }
  __syncthreads();

  if (t < 32) {
    float4 cap = red4[0][t];
    #pragma unroll
    for (int sg = 1; sg < 8; sg++) {
      float4 r = red4[sg][t];
      cap.x += r.x; cap.y += r.y; cap.z += r.z; cap.w += r.w;
    }
    float sq = cap.x * cap.x + cap.y * cap.y + cap.z * cap.z + cap.w * cap.w;
    #pragma unroll
    for (int o = 16; o; o >>= 1) sq += __shfl_xor(sq, o);
    const float n = sq;
    const float fac = n / (1.f + n) / sqrtf(n + 1e-9f);
    cap.x *= fac; cap.y *= fac; cap.z *= fac; cap.w *= fac;
    cq4[t] = cap;
    if (mode == 2)
      ((float4*)(out + ((size_t)b * KK + k) * HH))[t] = cap;
  }
  __syncthreads();

  if (mode < 2) {
    // phase 2: delta[s] = dot(hat[s][:], cq) — lane pair per s; global
    // chunk c = hh*8+j lives at physical (c+s)&15.
    const int s = t >> 1, hh = t & 1;
    float d = 0.f;
    #pragma unroll
    for (int j = 0; j < 8; j++) {
      const int c = hh * 8 + j;
      uint4 v = *(const uint4*)&hat_l[s * 128 + ((c + s) & 15) * 8];
      float4 qa = cq4[2 * c];
      float4 qb = cq4[2 * c + 1];
      d += bflo(v.x) * qa.x + bfhi(v.x) * qa.y
         + bflo(v.y) * qa.z + bfhi(v.y) * qa.w
         + bflo(v.z) * qb.x + bfhi(v.z) * qb.y
         + bflo(v.w) * qb.z + bfhi(v.w) * qb.w;
    }
    d += __shfl_xor(d, 1);
    if (hh == 0) {
      float* p = cw + ((size_t)k * SS + s) * BB + b;
      if (mode == 0) *p = d; else *p += d;
    }
  }
}

extern "C" void kernel_launch(void* const* d_in, const int* in_sizes, int n_in,
                              void* d_out, int out_size, void* d_ws, size_t ws_size,
                              hipStream_t stream) {
  const float* item_eb = (const float*)d_in[0];   // [B,S,H]
  const float* mask    = (const float*)d_in[1];   // [B,S]
  const float* w       = (const float*)d_in[2];   // [1,S,K*H,H]
  float* out = (float*)d_out;                     // [B,K,H]

  char* ws = (char*)d_ws;
  unsigned short* hat_bf  = (unsigned short*)ws;               // 67.1 MB [B][K][S][H]
  unsigned short* item_t  = (unsigned short*)(ws + 67108864);  // 16.8 MB [S][B][H]
  unsigned short* w_bf    = (unsigned short*)(ws + 83886080);  // 16.8 MB [S][D][H]
  float* cw  = (float*)(ws + 100663296);                       // 1 MB [K][S][B]
  float* swb = (float*)(ws + 101711872);                       // 1 MB [K][S][B]

  prep_k<<<dim3(9216), 256, 0, stream>>>(item_eb, w, item_t, w_bf);
  einsum_mfma<<<dim3(128, 16), 256, 0, stream>>>(item_t, w_bf, hat_bf);

  routing_k<<<dim3(BB, KK), 256, 0, stream>>>(hat_bf, mask, nullptr, cw, out, 0);
  softmax_k<<<dim3(SS, KK), 256, 0, stream>>>(cw, mask, swb);
  routing_k<<<dim3(BB, KK), 256, 0, stream>>>(hat_bf, mask, swb, cw, out, 1);
  softmax_k<<<dim3(SS, KK), 256, 0, stream>>>(cw, mask, swb);
  routing_k<<<dim3(BB, KK), 256, 0, stream>>>(hat_bf, mask, swb, cw, out, 2);
}